// Round 12
// baseline (4347.025 us; speedup 1.0000x reference)
//
#include <hip/hip_runtime.h>
#include <hip/hip_fp16.h>

// Problem constants
#define BB 64
#define TT 2048
#define II 128
#define HH 128
#define NG 512   // 4*H
#define CH 128   // pipeline chunk (steps)
#define NCH (TT / CH)
#define NA 4     // A (and B) workgroups; each handles 16 batches

typedef _Float16 h2_t __attribute__((ext_vector_type(2)));
typedef _Float16 f16x8 __attribute__((ext_vector_type(8)));
typedef float f32x4 __attribute__((ext_vector_type(4)));

#if defined(__has_builtin)
#if __has_builtin(__builtin_amdgcn_fdot2)
#define HAVE_FDOT2 1
#endif
#endif

__device__ __forceinline__ float fdot2f(h2_t a, h2_t b, float c) {
#ifdef HAVE_FDOT2
  return __builtin_amdgcn_fdot2(a, b, c, false);
#else
  return c + (float)a[0] * (float)b[0] + (float)a[1] * (float)b[1];
#endif
}

__device__ __forceinline__ float fast_sigmoid(float x) {
  float t = __builtin_amdgcn_exp2f(-1.4426950408889634f * x);
  return __builtin_amdgcn_rcpf(1.0f + t);
}
__device__ __forceinline__ float fast_tanh(float x) {
  return 2.0f * fast_sigmoid(2.0f * x) - 1.0f;
}

// LDS-only barrier: lgkmcnt drain + s_barrier (no vmcnt drain).
__device__ __forceinline__ void bar_lds() {
  __builtin_amdgcn_fence(__ATOMIC_RELEASE, "workgroup", "local");
  __builtin_amdgcn_s_barrier();
  __builtin_amdgcn_fence(__ATOMIC_ACQUIRE, "workgroup", "local");
}

union LDH {
  float4 f4;
  f16x8 h8;
};
union LDB {
  uint4 u4;
  h2_t h[4];
};
union XU {
  uint2 u;
  __half h[4];
};
union HP {
  _Float16 f[4];
  uint2 u;
};

__device__ __forceinline__ unsigned aload(unsigned* p) { return atomicAdd(p, 0u); }

// ---------------------------------------------------------------------------
// Transpose both Wx0 and Wx1: [512][128] -> [128][512]
// ---------------------------------------------------------------------------
__global__ void w_transpose2(const float* __restrict__ W0, float* __restrict__ T0,
                             const float* __restrict__ W1, float* __restrict__ T1) {
  int bid = blockIdx.x;
  const float* W = (bid < 256) ? W0 : W1;
  float* T = (bid < 256) ? T0 : T1;
  int idx = (bid & 255) * 256 + threadIdx.x;
  int n = idx >> 7;
  int k = idx & 127;
  T[k * NG + n] = W[idx];
}

// ---------------------------------------------------------------------------
// Xg0 = x @ Wx0^T + b0 -> f16 [B*T][512] (upfront, fully parallel)
// ---------------------------------------------------------------------------
__global__ __launch_bounds__(256) void xg_gemm(const float* __restrict__ X,
                                               const float* __restrict__ WT,
                                               const float* __restrict__ bias,
                                               __half* __restrict__ Xg) {
  __shared__ float As[64][132];
  __shared__ float Bs[128][64];
  const int m0 = blockIdx.x * 64;
  const int n0 = blockIdx.y * 64;
  const int tid = threadIdx.x;

  {
    const float4* xv = (const float4*)(X + (size_t)m0 * II);
#pragma unroll
    for (int r = 0; r < 8; ++r) {
      int f = tid + 256 * r;
      int m = f >> 5;
      int c4 = f & 31;
      float4 v = xv[m * 32 + c4];
      *(float4*)&As[m][c4 * 4] = v;
    }
  }
  {
#pragma unroll
    for (int r = 0; r < 8; ++r) {
      int f = tid + 256 * r;
      int k = f >> 4;
      int q = f & 15;
      float4 v = *(const float4*)(WT + (size_t)k * NG + n0 + q * 4);
      *(float4*)&Bs[k][q * 4] = v;
    }
  }
  __syncthreads();

  const int tx = tid & 15;
  const int ty = tid >> 4;
  float acc[4][4];
#pragma unroll
  for (int i = 0; i < 4; ++i)
#pragma unroll
    for (int j = 0; j < 4; ++j) acc[i][j] = 0.0f;

#pragma unroll 4
  for (int k = 0; k < 128; ++k) {
    float a0 = As[ty * 4 + 0][k];
    float a1 = As[ty * 4 + 1][k];
    float a2 = As[ty * 4 + 2][k];
    float a3 = As[ty * 4 + 3][k];
    float4 bv = *(const float4*)&Bs[k][tx * 4];
    acc[0][0] = fmaf(a0, bv.x, acc[0][0]);
    acc[0][1] = fmaf(a0, bv.y, acc[0][1]);
    acc[0][2] = fmaf(a0, bv.z, acc[0][2]);
    acc[0][3] = fmaf(a0, bv.w, acc[0][3]);
    acc[1][0] = fmaf(a1, bv.x, acc[1][0]);
    acc[1][1] = fmaf(a1, bv.y, acc[1][1]);
    acc[1][2] = fmaf(a1, bv.z, acc[1][2]);
    acc[1][3] = fmaf(a1, bv.w, acc[1][3]);
    acc[2][0] = fmaf(a2, bv.x, acc[2][0]);
    acc[2][1] = fmaf(a2, bv.y, acc[2][1]);
    acc[2][2] = fmaf(a2, bv.z, acc[2][2]);
    acc[2][3] = fmaf(a2, bv.w, acc[2][3]);
    acc[3][0] = fmaf(a3, bv.x, acc[3][0]);
    acc[3][1] = fmaf(a3, bv.y, acc[3][1]);
    acc[3][2] = fmaf(a3, bv.z, acc[3][2]);
    acc[3][3] = fmaf(a3, bv.w, acc[3][3]);
  }

  float4 bvec = *(const float4*)(bias + n0 + tx * 4);
#pragma unroll
  for (int i = 0; i < 4; ++i) {
    int m = m0 + ty * 4 + i;
    __half2* dst = (__half2*)(Xg + (size_t)m * NG + n0 + tx * 4);
    dst[0] = __halves2half2(__float2half(acc[i][0] + bvec.x),
                            __float2half(acc[i][1] + bvec.y));
    dst[1] = __halves2half2(__float2half(acc[i][2] + bvec.z),
                            __float2half(acc[i][3] + bvec.w));
  }
}

// ===========================================================================
// Mega kernel, 136 WGs:
//   [0,4):    role A — MFMA L0 recurrence, 16 batches/WG, writes hstream+flag0
//   [4,132):  role C — 2 WGs/batch chunk GEMM Xg1 = h0@Wx1^T + b1 (in place),
//             bumps flagCg[batch>>4]
//   [132,136): role B — MFMA L1 recurrence, 16 batches/WG, waits flagCg==32
// MFMA recurrence: wave w owns gate-aligned row-tiles {128r+16w..+15}, r=0..3
// (i,f,g,o). B-operand columns = 16 batches. After mfma, lane l holds all 4
// gates of units 16w+(l>>4)*4+q for batch l&15 at reg q -> in-register cell
// update, no LDS gate exchange. h dbuf LDS [2][16][136] f16 (+8 pad: banks).
// ===========================================================================
#define HROW 136          // padded h row (f16)
#define HBUF (16 * HROW)  // one h buffer (f16 count)

template <int LAYER>
__device__ __forceinline__ void role_rec(int g, int tid, char* smem,
    const __half* __restrict__ Xg, const float* __restrict__ Wh,
    float* __restrict__ out, __half* __restrict__ hstream,
    unsigned* flag0, unsigned* flagCg)
{
  const int w = tid >> 6;      // wave = unit-block
  const int l = tid & 63;
  const int lrow = l & 15;     // A-frag row within tile / D col (batch)
  const int lk = l >> 4;       // k-group / D row-group
  const int u0 = 16 * w + lk * 4;   // first of 4 units this lane updates
  const int bg = 16 * g + lrow;     // global batch this lane updates

  // Stationary weight fragments: wf[r][kt] row = 128r+16w+lrow, k = 32kt+8lk+j
  f16x8 wf[4][4];
#pragma unroll
  for (int r = 0; r < 4; ++r)
#pragma unroll
    for (int kt = 0; kt < 4; ++kt) {
      const float4* s4 = (const float4*)(Wh + (size_t)(128 * r + 16 * w + lrow) * HH + 32 * kt + 8 * lk);
      float4 v0 = s4[0], v1 = s4[1];
      f16x8 f;
      f[0] = (_Float16)v0.x; f[1] = (_Float16)v0.y; f[2] = (_Float16)v0.z; f[3] = (_Float16)v0.w;
      f[4] = (_Float16)v1.x; f[5] = (_Float16)v1.y; f[6] = (_Float16)v1.z; f[7] = (_Float16)v1.w;
      wf[r][kt] = f;
    }

  // h double buffer in LDS
  _Float16* hb = (_Float16*)smem;
  for (int i = tid; i < 2 * HBUF; i += 512) hb[i] = (_Float16)0.0f;
  float c[4] = {0.f, 0.f, 0.f, 0.f};
  float hq[4] = {0.f, 0.f, 0.f, 0.f};
  __syncthreads();

  const __half* XgL = Xg + (size_t)bg * TT * NG + u0;   // + t*NG + 128r + q
  float* hT = out + (size_t)BB * TT * HH;
  float* cT = hT + 2 * BB * HH;
  float* outp = out + (size_t)bg * TT * HH + u0;        // B writes
  __half* hsp = hstream + (size_t)bg * TT * HH + u0;    // A writes

  char* hbc = (char*)smem;
  const int rdoff = lrow * (HROW * 2) + lk * 16;        // B-frag byte offset
  const int wroff = lrow * (HROW * 2) + u0 * 2;         // h-write byte offset

  XU xc[4];
  if (LAYER == 0) {
#pragma unroll
    for (int r = 0; r < 4; ++r) xc[r].u = *(const uint2*)(XgL + r * 128);
  }

#pragma unroll 1
  for (int cc = 0; cc < NCH; ++cc) {
    if (LAYER == 1) {
      if (tid == 0) {
        while (aload(flagCg + g * NCH + cc) < 32u) __builtin_amdgcn_s_sleep(1);
      }
      __syncthreads();
      __builtin_amdgcn_fence(__ATOMIC_ACQUIRE, "agent");
      const __half* xb = XgL + (size_t)(cc * CH) * NG;
#pragma unroll
      for (int r = 0; r < 4; ++r) xc[r].u = *(const uint2*)(xb + r * 128);
    }

#pragma unroll 1
    for (int s = 0; s < CH; ++s) {
      const int t = cc * CH + s;

      // ---- B-frags from h LDS + 16 mfma ----
      const char* hr = hbc + (t & 1) * (HBUF * 2) + rdoff;
      f32x4 a0 = {0.f, 0.f, 0.f, 0.f};
      f32x4 a1 = a0, a2 = a0, a3 = a0;
#pragma unroll
      for (int kt = 0; kt < 4; ++kt) {
        LDH u;
        u.f4 = *(const float4*)(hr + kt * 64);
        a0 = __builtin_amdgcn_mfma_f32_16x16x32_f16(wf[0][kt], u.h8, a0, 0, 0, 0);
        a1 = __builtin_amdgcn_mfma_f32_16x16x32_f16(wf[1][kt], u.h8, a1, 0, 0, 0);
        a2 = __builtin_amdgcn_mfma_f32_16x16x32_f16(wf[2][kt], u.h8, a2, 0, 0, 0);
        a3 = __builtin_amdgcn_mfma_f32_16x16x32_f16(wf[3][kt], u.h8, a3, 0, 0, 0);
      }

      // ---- prefetch next step's Xg (A: free across chunks; B: within chunk)
      XU xn[4];
      const bool pf = (LAYER == 0) ? (t + 1 < TT) : (s + 1 < CH);
      if (pf) {
        const __half* xb = XgL + (size_t)(t + 1) * NG;
#pragma unroll
        for (int r = 0; r < 4; ++r) xn[r].u = *(const uint2*)(xb + r * 128);
      }

      // ---- elementwise: 4 units, all gates in-lane ----
      HP hp;
#pragma unroll
      for (int q = 0; q < 4; ++q) {
        float gi = fast_sigmoid(a0[q] + __half2float(xc[0].h[q]));
        float gf = fast_sigmoid(a1[q] + __half2float(xc[1].h[q]));
        float gg = fast_tanh(a2[q] + __half2float(xc[2].h[q]));
        float go = fast_sigmoid(a3[q] + __half2float(xc[3].h[q]));
        c[q] = gf * c[q] + gi * gg;
        float h = go * fast_tanh(c[q]);
        hq[q] = h;
        hp.f[q] = (_Float16)h;
      }
      // h -> next LDS buffer (8B), plus global stream/output
      *(uint2*)(hbc + ((t & 1) ^ 1) * (HBUF * 2) + wroff) = hp.u;
      if (LAYER == 0) {
        *(uint2*)(hsp + (size_t)t * HH) = hp.u;
      } else {
        float4 o4 = {hq[0], hq[1], hq[2], hq[3]};
        *(float4*)(outp + (size_t)t * HH) = o4;
      }
      bar_lds();
#pragma unroll
      for (int r = 0; r < 4; ++r) xc[r].u = xn[r].u;
    }

    if (LAYER == 0) {
      __syncthreads();   // drain hstream stores (vmcnt)
      __builtin_amdgcn_fence(__ATOMIC_RELEASE, "agent");
      if (tid < 16) atomicExch(flag0 + (16 * g + tid) * NCH + cc, 1u);
    }
  }

  // final states
  float4 hv4 = {hq[0], hq[1], hq[2], hq[3]};
  float4 cv4 = {c[0], c[1], c[2], c[3]};
  *(float4*)(hT + (size_t)LAYER * BB * HH + (size_t)bg * HH + u0) = hv4;
  *(float4*)(cT + (size_t)LAYER * BB * HH + (size_t)bg * HH + u0) = cv4;
}

// ---- role C: chunk GEMM Xg1(chunk) = h0(chunk) @ Wx1^T + b1 (f16 dot2) ----
__device__ __forceinline__ void roleC(int cidx, int n, char* smem,
    __half* Xg, const __half* hstream, const float* __restrict__ WT1,
    const float* __restrict__ b1, unsigned* flag0, unsigned* flagCg)
{
  const int b = cidx >> 1;
  const int half = cidx & 1;
  h2_t(*As2)[68] = (h2_t(*)[68])smem;                    // [64][68] h2
  h2_t(*Bs2)[64] = (h2_t(*)[64])(smem + 64 * 68 * 4);    // [64][64] h2

  const int ty = n >> 4;
  const int tx = n & 15;

#pragma unroll 1
  for (int cc = 0; cc < NCH; ++cc) {
    if (n == 0) {
      while (aload(flag0 + b * NCH + cc) < 1u) __builtin_amdgcn_s_sleep(1);
    }
    __syncthreads();
    __builtin_amdgcn_fence(__ATOMIC_ACQUIRE, "agent");

    const int t0 = cc * CH + half * 64;
    {
      const int m = n >> 3, seg = n & 7;
      const uint4* src = (const uint4*)(hstream + ((size_t)b * TT + t0 + m) * HH + seg * 16);
      uint4 v0 = src[0], v1 = src[1];
      *(uint4*)&As2[m][seg * 8] = v0;
      *(uint4*)&As2[m][seg * 8 + 4] = v1;
    }

#pragma unroll 1
    for (int nt = 0; nt < 8; ++nt) {
      __syncthreads();
      {
        const int kp = n >> 3, cg = n & 7;
        const float4* w0 = (const float4*)(WT1 + (size_t)(2 * kp) * NG + nt * 64 + cg * 8);
        const float4* w1 = (const float4*)(WT1 + (size_t)(2 * kp + 1) * NG + nt * 64 + cg * 8);
        float4 x0 = w0[0], x1 = w0[1];
        float4 y0 = w1[0], y1 = w1[1];
        h2_t r[8];
        r[0][0] = (_Float16)x0.x; r[0][1] = (_Float16)y0.x;
        r[1][0] = (_Float16)x0.y; r[1][1] = (_Float16)y0.y;
        r[2][0] = (_Float16)x0.z; r[2][1] = (_Float16)y0.z;
        r[3][0] = (_Float16)x0.w; r[3][1] = (_Float16)y0.w;
        r[4][0] = (_Float16)x1.x; r[4][1] = (_Float16)y1.x;
        r[5][0] = (_Float16)x1.y; r[5][1] = (_Float16)y1.y;
        r[6][0] = (_Float16)x1.z; r[6][1] = (_Float16)y1.z;
        r[7][0] = (_Float16)x1.w; r[7][1] = (_Float16)y1.w;
        *(uint4*)&Bs2[kp][cg * 8] = *(uint4*)&r[0];
        *(uint4*)&Bs2[kp][cg * 8 + 4] = *(uint4*)&r[4];
      }
      __syncthreads();

      float acc[2][4];
#pragma unroll
      for (int r = 0; r < 2; ++r)
#pragma unroll
        for (int q = 0; q < 4; ++q) acc[r][q] = 0.0f;

#pragma unroll 4
      for (int k4 = 0; k4 < 16; ++k4) {
        LDB ua0, ua1;
        ua0.u4 = *(const uint4*)&As2[ty * 2][k4 * 4];
        ua1.u4 = *(const uint4*)&As2[ty * 2 + 1][k4 * 4];
#pragma unroll
        for (int t = 0; t < 4; ++t) {
          LDB ub;
          ub.u4 = *(const uint4*)&Bs2[k4 * 4 + t][tx * 4];
          acc[0][0] = fdot2f(ua0.h[t], ub.h[0], acc[0][0]);
          acc[0][1] = fdot2f(ua0.h[t], ub.h[1], acc[0][1]);
          acc[0][2] = fdot2f(ua0.h[t], ub.h[2], acc[0][2]);
          acc[0][3] = fdot2f(ua0.h[t], ub.h[3], acc[0][3]);
          acc[1][0] = fdot2f(ua1.h[t], ub.h[0], acc[1][0]);
          acc[1][1] = fdot2f(ua1.h[t], ub.h[1], acc[1][1]);
          acc[1][2] = fdot2f(ua1.h[t], ub.h[2], acc[1][2]);
          acc[1][3] = fdot2f(ua1.h[t], ub.h[3], acc[1][3]);
        }
      }

      const int col = nt * 64 + tx * 4;
      float4 bv = *(const float4*)(b1 + col);
#pragma unroll
      for (int r = 0; r < 2; ++r) {
        __half2* d = (__half2*)(Xg + ((size_t)b * TT + t0 + ty * 2 + r) * NG + col);
        d[0] = __halves2half2(__float2half(acc[r][0] + bv.x),
                              __float2half(acc[r][1] + bv.y));
        d[1] = __halves2half2(__float2half(acc[r][2] + bv.z),
                              __float2half(acc[r][3] + bv.w));
      }
    }
    __syncthreads();
    if (n == 0) {
      __builtin_amdgcn_fence(__ATOMIC_RELEASE, "agent");
      atomicAdd(flagCg + (b >> 4) * NCH + cc, 1u);
    }
  }
}

__global__
__attribute__((amdgpu_flat_work_group_size(512, 512)))
void lstm_mega(__half* Xg, __half* hstream,
               const float* __restrict__ Wh0,
               const float* __restrict__ Wh1,
               const float* __restrict__ WT1,
               const float* __restrict__ b1,
               float* __restrict__ out,
               unsigned* flag0, unsigned* flagCg)
{
  __shared__ __align__(16) char smem[64 * 68 * 4 + 64 * 64 * 4];  // 33792B
  const int bid = blockIdx.x;
  const int tid = threadIdx.x;
  if (bid < NA) {
    role_rec<0>(bid, tid, smem, Xg, Wh0, out, hstream, flag0, flagCg);
  } else if (bid < NA + 2 * BB) {
    roleC(bid - NA, tid, smem, Xg, hstream, WT1, b1, flag0, flagCg);
  } else {
    role_rec<1>(bid - NA - 2 * BB, tid, smem, Xg, Wh1, out, hstream, flag0, flagCg);
  }
}

// ---------------------------------------------------------------------------
extern "C" void kernel_launch(void* const* d_in, const int* in_sizes, int n_in,
                              void* d_out, int out_size, void* d_ws, size_t ws_size,
                              hipStream_t stream) {
  const float* x   = (const float*)d_in[0];
  const float* Wx0 = (const float*)d_in[1];
  const float* Wh0 = (const float*)d_in[2];
  const float* b0  = (const float*)d_in[3];
  const float* Wx1 = (const float*)d_in[4];
  const float* Wh1 = (const float*)d_in[5];
  const float* b1  = (const float*)d_in[6];
  float* out = (float*)d_out;

  // ws: Xg f16 [B*T][512] | hstream f16 [B*T][128] | WT0 | WT1 | flag0|flagCg
  char* base = (char*)d_ws;
  __half* Xg = (__half*)base;
  size_t off = (size_t)BB * TT * NG * sizeof(__half);      // 128 MB
  __half* hstream = (__half*)(base + off);
  off += (size_t)BB * TT * HH * sizeof(__half);            // +32 MB
  float* WT0 = (float*)(base + off);
  off += (size_t)II * NG * sizeof(float);
  float* WT1 = (float*)(base + off);
  off += (size_t)II * NG * sizeof(float);
  unsigned* flag0 = (unsigned*)(base + off);
  unsigned* flagCg = flag0 + BB * NCH;

  hipMemsetAsync(flag0, 0, (size_t)(BB * NCH + NA * NCH) * sizeof(unsigned), stream);
  w_transpose2<<<512, 256, 0, stream>>>(Wx0, WT0, Wx1, WT1);
  xg_gemm<<<dim3((BB * TT) / 64, NG / 64), 256, 0, stream>>>(x, WT0, b0, Xg);
  lstm_mega<<<NA + 2 * BB + NA, 512, 0, stream>>>(Xg, hstream, Wh0, Wh1, WT1,
                                                  b1, out, flag0, flagCg);
}

// Round 13
// 1432.862 us; speedup vs baseline: 3.0338x; 3.0338x over previous
//
#include <hip/hip_runtime.h>
#include <hip/hip_fp16.h>

// Problem constants
#define BB 64
#define TT 2048
#define II 128
#define HH 128
#define NG 512   // 4*H
#define CH 128   // pipeline chunk (steps)
#define NCH (TT / CH)

typedef _Float16 h2_t __attribute__((ext_vector_type(2)));

#if defined(__has_builtin)
#if __has_builtin(__builtin_amdgcn_fdot2)
#define HAVE_FDOT2 1
#endif
#endif

__device__ __forceinline__ float fdot2f(h2_t a, h2_t b, float c) {
#ifdef HAVE_FDOT2
  return __builtin_amdgcn_fdot2(a, b, c, false);
#else
  return c + (float)a[0] * (float)b[0] + (float)a[1] * (float)b[1];
#endif
}

__device__ __forceinline__ float fast_sigmoid(float x) {
  float t = __builtin_amdgcn_exp2f(-1.4426950408889634f * x);
  return __builtin_amdgcn_rcpf(1.0f + t);
}
__device__ __forceinline__ float act_gate(float x, bool tanh_sel) {
  float xx = tanh_sel ? 2.0f * x : x;
  float s = fast_sigmoid(xx);
  return tanh_sel ? 2.0f * s - 1.0f : s;
}
__device__ __forceinline__ float fast_tanh(float x) {
  return 2.0f * fast_sigmoid(2.0f * x) - 1.0f;
}

__device__ __forceinline__ float dpp_xor1(float x) {
  return __int_as_float(__builtin_amdgcn_update_dpp(0, __float_as_int(x), 0xB1, 0xF, 0xF, true));
}
__device__ __forceinline__ float dpp_xor2(float x) {
  return __int_as_float(__builtin_amdgcn_update_dpp(0, __float_as_int(x), 0x4E, 0xF, 0xF, true));
}

// LDS-only barrier: lgkmcnt drain + s_barrier (no vmcnt drain).
__device__ __forceinline__ void bar_lds() {
  __builtin_amdgcn_fence(__ATOMIC_RELEASE, "workgroup", "local");
  __builtin_amdgcn_s_barrier();
  __builtin_amdgcn_fence(__ATOMIC_ACQUIRE, "workgroup", "local");
}

union LD4 {
  float4 f4;
  h2_t h[4];
};
union LDB {
  uint4 u4;
  h2_t h[4];
};

__device__ __forceinline__ unsigned aload(unsigned* p) { return atomicAdd(p, 0u); }

// ---------------------------------------------------------------------------
// Transpose both Wx0 and Wx1: [512][128] -> [128][512]
// ---------------------------------------------------------------------------
__global__ void w_transpose2(const float* __restrict__ W0, float* __restrict__ T0,
                             const float* __restrict__ W1, float* __restrict__ T1) {
  int bid = blockIdx.x;
  const float* W = (bid < 256) ? W0 : W1;
  float* T = (bid < 256) ? T0 : T1;
  int idx = (bid & 255) * 256 + threadIdx.x;
  int n = idx >> 7;
  int k = idx & 127;
  T[k * NG + n] = W[idx];
}

// ---------------------------------------------------------------------------
// Prologue GEMM: Xg0 for chunks 0..1 only (rows [b*TT, b*TT+2*CH) per batch).
// grid.x = BB*4 (4 row-blocks of 64 = 256 rows/batch), grid.y = 8.
// ---------------------------------------------------------------------------
__global__ __launch_bounds__(256) void xg_gemm_pro(const float* __restrict__ X,
                                                   const float* __restrict__ WT,
                                                   const float* __restrict__ bias,
                                                   __half* __restrict__ Xg) {
  __shared__ float As[64][132];
  __shared__ float Bs[128][64];
  const int bx = blockIdx.x;
  const size_t m0 = (size_t)(bx >> 2) * TT + (bx & 3) * 64;
  const int n0 = blockIdx.y * 64;
  const int tid = threadIdx.x;

  {
    const float4* xv = (const float4*)(X + m0 * II);
#pragma unroll
    for (int r = 0; r < 8; ++r) {
      int f = tid + 256 * r;
      int m = f >> 5;
      int c4 = f & 31;
      float4 v = xv[m * 32 + c4];
      *(float4*)&As[m][c4 * 4] = v;
    }
  }
  {
#pragma unroll
    for (int r = 0; r < 8; ++r) {
      int f = tid + 256 * r;
      int k = f >> 4;
      int q = f & 15;
      float4 v = *(const float4*)(WT + (size_t)k * NG + n0 + q * 4);
      *(float4*)&Bs[k][q * 4] = v;
    }
  }
  __syncthreads();

  const int tx = tid & 15;
  const int ty = tid >> 4;
  float acc[4][4];
#pragma unroll
  for (int i = 0; i < 4; ++i)
#pragma unroll
    for (int j = 0; j < 4; ++j) acc[i][j] = 0.0f;

#pragma unroll 4
  for (int k = 0; k < 128; ++k) {
    float a0 = As[ty * 4 + 0][k];
    float a1 = As[ty * 4 + 1][k];
    float a2 = As[ty * 4 + 2][k];
    float a3 = As[ty * 4 + 3][k];
    float4 bv = *(const float4*)&Bs[k][tx * 4];
    acc[0][0] = fmaf(a0, bv.x, acc[0][0]);
    acc[0][1] = fmaf(a0, bv.y, acc[0][1]);
    acc[0][2] = fmaf(a0, bv.z, acc[0][2]);
    acc[0][3] = fmaf(a0, bv.w, acc[0][3]);
    acc[1][0] = fmaf(a1, bv.x, acc[1][0]);
    acc[1][1] = fmaf(a1, bv.y, acc[1][1]);
    acc[1][2] = fmaf(a1, bv.z, acc[1][2]);
    acc[1][3] = fmaf(a1, bv.w, acc[1][3]);
    acc[2][0] = fmaf(a2, bv.x, acc[2][0]);
    acc[2][1] = fmaf(a2, bv.y, acc[2][1]);
    acc[2][2] = fmaf(a2, bv.z, acc[2][2]);
    acc[2][3] = fmaf(a2, bv.w, acc[2][3]);
    acc[3][0] = fmaf(a3, bv.x, acc[3][0]);
    acc[3][1] = fmaf(a3, bv.y, acc[3][1]);
    acc[3][2] = fmaf(a3, bv.z, acc[3][2]);
    acc[3][3] = fmaf(a3, bv.w, acc[3][3]);
  }

  float4 bvec = *(const float4*)(bias + n0 + tx * 4);
#pragma unroll
  for (int i = 0; i < 4; ++i) {
    size_t m = m0 + ty * 4 + i;
    __half2* dst = (__half2*)(Xg + m * NG + n0 + tx * 4);
    dst[0] = __halves2half2(__float2half(acc[i][0] + bvec.x),
                            __float2half(acc[i][1] + bvec.y));
    dst[1] = __halves2half2(__float2half(acc[i][2] + bvec.z),
                            __float2half(acc[i][3] + bvec.w));
  }
}

// ===========================================================================
// Mega kernel: 256 WGs.
//   [0,64):    role A — L0 recurrence (waits flagX for cc>=2), flag0/chunk
//   [64,192):  role C — per iter cc: Xg0(cc+2)=x@Wx0^T+b0 -> flagX, then
//              wait flag0(cc) -> Xg1(cc)=h0@Wx1^T+b1 (in place) -> flagC
//   [192,256): role B — L1 recurrence on Xg1 chunks (waits flagC>=2)
// ===========================================================================

// ---- role A: layer-0 recurrence, 8 accumulation chains ----
__device__ __forceinline__ void roleA(int b, int n, char* smem,
    const __half* Xg, const float* __restrict__ Wh0,
    float* __restrict__ out, __half* hstream,
    unsigned* flag0, unsigned* flagX)
{
  const int j = n >> 2;
  const int p = n & 3;
  const bool tsel = (p == 2);

  h2_t wh[4][16];
#pragma unroll
  for (int g = 0; g < 4; ++g) {
    const float2* ph = (const float2*)(Wh0 + (size_t)(g * 128 + j) * HH + p * 32);
#pragma unroll
    for (int k = 0; k < 16; ++k) {
      float2 v = ph[k];
      wh[g][k][0] = (_Float16)v.x;
      wh[g][k][1] = (_Float16)v.y;
    }
  }

  _Float16(*hb)[HH] = (_Float16(*)[HH])smem;
  if (n < HH) {
    hb[0][n] = (_Float16)0.0f;
    hb[1][n] = (_Float16)0.0f;
  }
  float c = 0.0f, hv = 0.0f;
  __syncthreads();

  const __half* xs = Xg + (size_t)b * TT * NG + p * 128 + j;
  float* hT = out + (size_t)BB * TT * HH;
  float* cT = hT + 2 * BB * HH;
  __half* hsp = hstream + (size_t)b * TT * HH + j;

#pragma unroll 1
  for (int cc = 0; cc < NCH; ++cc) {
    if (cc >= 2) {
      if (n == 0) {
        while (aload(flagX + b * NCH + cc) < 2u) __builtin_amdgcn_s_sleep(1);
      }
      __syncthreads();
      __builtin_amdgcn_fence(__ATOMIC_ACQUIRE, "agent");
    }
    __half xg_c = xs[(size_t)(cc * CH) * NG];

#pragma unroll 1
    for (int s = 0; s < CH; ++s) {
      const int i = cc * CH + s;
      __half xg_n = (s + 1 < CH) ? xs[(size_t)(i + 1) * NG] : __float2half(0.0f);

      const char* H = (const char*)hb[i & 1] + p * 64;
      // 8 chains: per row r, chain a (t=0,1) and chain b (t=2,3)
      float s0a = 0.f, s0b = 0.f, s1a = 0.f, s1b = 0.f;
      float s2a = 0.f, s2b = 0.f, s3a = 0.f, s3b = 0.f;
#pragma unroll
      for (int q = 0; q < 4; ++q) {
        LD4 u;
        u.f4 = *(const float4*)(H + q * 16);
        const int m = q * 4;
        s0a = fdot2f(wh[0][m + 0], u.h[0], s0a);
        s0b = fdot2f(wh[0][m + 2], u.h[2], s0b);
        s1a = fdot2f(wh[1][m + 0], u.h[0], s1a);
        s1b = fdot2f(wh[1][m + 2], u.h[2], s1b);
        s2a = fdot2f(wh[2][m + 0], u.h[0], s2a);
        s2b = fdot2f(wh[2][m + 2], u.h[2], s2b);
        s3a = fdot2f(wh[3][m + 0], u.h[0], s3a);
        s3b = fdot2f(wh[3][m + 2], u.h[2], s3b);
        s0a = fdot2f(wh[0][m + 1], u.h[1], s0a);
        s0b = fdot2f(wh[0][m + 3], u.h[3], s0b);
        s1a = fdot2f(wh[1][m + 1], u.h[1], s1a);
        s1b = fdot2f(wh[1][m + 3], u.h[3], s1b);
        s2a = fdot2f(wh[2][m + 1], u.h[1], s2a);
        s2b = fdot2f(wh[2][m + 3], u.h[3], s2b);
        s3a = fdot2f(wh[3][m + 1], u.h[1], s3a);
        s3b = fdot2f(wh[3][m + 3], u.h[3], s3b);
      }
      float a0 = s0a + s0b, a1 = s1a + s1b, a2 = s2a + s2b, a3 = s3a + s3b;

      float k01 = (p & 1) ? a1 : a0;
      float u01 = (p & 1) ? a0 : a1;
      float r01 = k01 + dpp_xor1(u01);
      float k23 = (p & 1) ? a3 : a2;
      float u23 = (p & 1) ? a2 : a3;
      float r23 = k23 + dpp_xor1(u23);
      float kA = (p & 2) ? r23 : r01;
      float uA = (p & 2) ? r01 : r23;
      float sL = kA + dpp_xor2(uA);
      float aL = act_gate(sL + __half2float(xg_c), tsel);
      float fg = dpp_xor1(aL);
      float gg = dpp_xor2(aL);
      float og = dpp_xor2(fg);
      if (p == 0) {
        c = fg * c + aL * gg;
        hv = og * fast_tanh(c);
        _Float16 hf = (_Float16)hv;
        hb[(i & 1) ^ 1][j] = hf;
        *(_Float16*)(hsp + (size_t)i * HH) = hf;
      }
      bar_lds();
      xg_c = xg_n;
    }
    __syncthreads();   // drains hstream stores (vmcnt)
    if (n == 0) {
      __builtin_amdgcn_fence(__ATOMIC_RELEASE, "agent");
      atomicExch(flag0 + b * NCH + cc, 1u);
    }
  }

  if (p == 0) {
    hT[b * HH + j] = hv;
    cT[b * HH + j] = c;
  }
}

// ---- role C: Xg0(cc+2) production then Xg1(cc) bridge GEMM ----
__device__ __forceinline__ void roleC(int cidx, int n, char* smem,
    __half* Xg, const __half* hstream, const float* __restrict__ x,
    const float* __restrict__ WT0, const float* __restrict__ b0,
    const float* __restrict__ WT1, const float* __restrict__ b1,
    unsigned* flag0, unsigned* flagC, unsigned* flagX)
{
  const int b = cidx >> 1;
  const int half = cidx & 1;
  h2_t(*As2)[68] = (h2_t(*)[68])smem;                    // [64][68] h2
  h2_t(*Bs2)[64] = (h2_t(*)[64])(smem + 64 * 68 * 4);    // [64][64] h2

  const int ty = n >> 4;
  const int tx = n & 15;
  const int mf = n >> 3;   // fill row
  const int sf = n & 7;    // fill segment

#pragma unroll 1
  for (int cc = 0; cc < NCH; ++cc) {
    // ======== part X0: Xg0 for chunk cc+2 (input-only, no waits) ========
    if (cc + 2 < NCH) {
      const int t0x = (cc + 2) * CH + half * 64;
      // fill As2 from x (f32 -> f16)
      {
        const float4* sx = (const float4*)(x + ((size_t)b * TT + t0x + mf) * II + sf * 16);
        float4 p0 = sx[0], p1 = sx[1], p2 = sx[2], p3 = sx[3];
        h2_t r[8];
        r[0][0] = (_Float16)p0.x; r[0][1] = (_Float16)p0.y;
        r[1][0] = (_Float16)p0.z; r[1][1] = (_Float16)p0.w;
        r[2][0] = (_Float16)p1.x; r[2][1] = (_Float16)p1.y;
        r[3][0] = (_Float16)p1.z; r[3][1] = (_Float16)p1.w;
        r[4][0] = (_Float16)p2.x; r[4][1] = (_Float16)p2.y;
        r[5][0] = (_Float16)p2.z; r[5][1] = (_Float16)p2.w;
        r[6][0] = (_Float16)p3.x; r[6][1] = (_Float16)p3.y;
        r[7][0] = (_Float16)p3.z; r[7][1] = (_Float16)p3.w;
        *(uint4*)&As2[mf][sf * 8] = *(uint4*)&r[0];
        *(uint4*)&As2[mf][sf * 8 + 4] = *(uint4*)&r[4];
      }
#pragma unroll 1
      for (int nt = 0; nt < 8; ++nt) {
        __syncthreads();
        {
          const int kp = n >> 3, cg = n & 7;
          const float4* w0 = (const float4*)(WT0 + (size_t)(2 * kp) * NG + nt * 64 + cg * 8);
          const float4* w1 = (const float4*)(WT0 + (size_t)(2 * kp + 1) * NG + nt * 64 + cg * 8);
          float4 x0 = w0[0], x1 = w0[1];
          float4 y0 = w1[0], y1 = w1[1];
          h2_t r[8];
          r[0][0] = (_Float16)x0.x; r[0][1] = (_Float16)y0.x;
          r[1][0] = (_Float16)x0.y; r[1][1] = (_Float16)y0.y;
          r[2][0] = (_Float16)x0.z; r[2][1] = (_Float16)y0.z;
          r[3][0] = (_Float16)x0.w; r[3][1] = (_Float16)y0.w;
          r[4][0] = (_Float16)x1.x; r[4][1] = (_Float16)y1.x;
          r[5][0] = (_Float16)x1.y; r[5][1] = (_Float16)y1.y;
          r[6][0] = (_Float16)x1.z; r[6][1] = (_Float16)y1.z;
          r[7][0] = (_Float16)x1.w; r[7][1] = (_Float16)y1.w;
          *(uint4*)&Bs2[kp][cg * 8] = *(uint4*)&r[0];
          *(uint4*)&Bs2[kp][cg * 8 + 4] = *(uint4*)&r[4];
        }
        __syncthreads();

        float acc[2][4];
#pragma unroll
        for (int r = 0; r < 2; ++r)
#pragma unroll
          for (int q = 0; q < 4; ++q) acc[r][q] = 0.0f;
#pragma unroll 4
        for (int k4 = 0; k4 < 16; ++k4) {
          LDB ua0, ua1;
          ua0.u4 = *(const uint4*)&As2[ty * 2][k4 * 4];
          ua1.u4 = *(const uint4*)&As2[ty * 2 + 1][k4 * 4];
#pragma unroll
          for (int t = 0; t < 4; ++t) {
            LDB ub;
            ub.u4 = *(const uint4*)&Bs2[k4 * 4 + t][tx * 4];
            acc[0][0] = fdot2f(ua0.h[t], ub.h[0], acc[0][0]);
            acc[0][1] = fdot2f(ua0.h[t], ub.h[1], acc[0][1]);
            acc[0][2] = fdot2f(ua0.h[t], ub.h[2], acc[0][2]);
            acc[0][3] = fdot2f(ua0.h[t], ub.h[3], acc[0][3]);
            acc[1][0] = fdot2f(ua1.h[t], ub.h[0], acc[1][0]);
            acc[1][1] = fdot2f(ua1.h[t], ub.h[1], acc[1][1]);
            acc[1][2] = fdot2f(ua1.h[t], ub.h[2], acc[1][2]);
            acc[1][3] = fdot2f(ua1.h[t], ub.h[3], acc[1][3]);
          }
        }
        const int col = nt * 64 + tx * 4;
        float4 bv = *(const float4*)(b0 + col);
#pragma unroll
        for (int r = 0; r < 2; ++r) {
          __half2* d = (__half2*)(Xg + ((size_t)b * TT + t0x + ty * 2 + r) * NG + col);
          d[0] = __halves2half2(__float2half(acc[r][0] + bv.x),
                                __float2half(acc[r][1] + bv.y));
          d[1] = __halves2half2(__float2half(acc[r][2] + bv.z),
                                __float2half(acc[r][3] + bv.w));
        }
      }
      __syncthreads();   // drain Xg0 stores + protect As2
      if (n == 0) {
        __builtin_amdgcn_fence(__ATOMIC_RELEASE, "agent");
        atomicAdd(flagX + b * NCH + cc + 2, 1u);
      }
    }

    // ======== part X1: Xg1 for chunk cc (waits on h0) ========
    if (n == 0) {
      while (aload(flag0 + b * NCH + cc) < 1u) __builtin_amdgcn_s_sleep(1);
    }
    __syncthreads();
    __builtin_amdgcn_fence(__ATOMIC_ACQUIRE, "agent");

    const int t0 = cc * CH + half * 64;
    {
      const uint4* src = (const uint4*)(hstream + ((size_t)b * TT + t0 + mf) * HH + sf * 16);
      uint4 v0 = src[0], v1 = src[1];
      *(uint4*)&As2[mf][sf * 8] = v0;
      *(uint4*)&As2[mf][sf * 8 + 4] = v1;
    }
#pragma unroll 1
    for (int nt = 0; nt < 8; ++nt) {
      __syncthreads();
      {
        const int kp = n >> 3, cg = n & 7;
        const float4* w0 = (const float4*)(WT1 + (size_t)(2 * kp) * NG + nt * 64 + cg * 8);
        const float4* w1 = (const float4*)(WT1 + (size_t)(2 * kp + 1) * NG + nt * 64 + cg * 8);
        float4 x0 = w0[0], x1 = w0[1];
        float4 y0 = w1[0], y1 = w1[1];
        h2_t r[8];
        r[0][0] = (_Float16)x0.x; r[0][1] = (_Float16)y0.x;
        r[1][0] = (_Float16)x0.y; r[1][1] = (_Float16)y0.y;
        r[2][0] = (_Float16)x0.z; r[2][1] = (_Float16)y0.z;
        r[3][0] = (_Float16)x0.w; r[3][1] = (_Float16)y0.w;
        r[4][0] = (_Float16)x1.x; r[4][1] = (_Float16)y1.x;
        r[5][0] = (_Float16)x1.y; r[5][1] = (_Float16)y1.y;
        r[6][0] = (_Float16)x1.z; r[6][1] = (_Float16)y1.z;
        r[7][0] = (_Float16)x1.w; r[7][1] = (_Float16)y1.w;
        *(uint4*)&Bs2[kp][cg * 8] = *(uint4*)&r[0];
        *(uint4*)&Bs2[kp][cg * 8 + 4] = *(uint4*)&r[4];
      }
      __syncthreads();

      float acc[2][4];
#pragma unroll
      for (int r = 0; r < 2; ++r)
#pragma unroll
        for (int q = 0; q < 4; ++q) acc[r][q] = 0.0f;
#pragma unroll 4
      for (int k4 = 0; k4 < 16; ++k4) {
        LDB ua0, ua1;
        ua0.u4 = *(const uint4*)&As2[ty * 2][k4 * 4];
        ua1.u4 = *(const uint4*)&As2[ty * 2 + 1][k4 * 4];
#pragma unroll
        for (int t = 0; t < 4; ++t) {
          LDB ub;
          ub.u4 = *(const uint4*)&Bs2[k4 * 4 + t][tx * 4];
          acc[0][0] = fdot2f(ua0.h[t], ub.h[0], acc[0][0]);
          acc[0][1] = fdot2f(ua0.h[t], ub.h[1], acc[0][1]);
          acc[0][2] = fdot2f(ua0.h[t], ub.h[2], acc[0][2]);
          acc[0][3] = fdot2f(ua0.h[t], ub.h[3], acc[0][3]);
          acc[1][0] = fdot2f(ua1.h[t], ub.h[0], acc[1][0]);
          acc[1][1] = fdot2f(ua1.h[t], ub.h[1], acc[1][1]);
          acc[1][2] = fdot2f(ua1.h[t], ub.h[2], acc[1][2]);
          acc[1][3] = fdot2f(ua1.h[t], ub.h[3], acc[1][3]);
        }
      }
      const int col = nt * 64 + tx * 4;
      float4 bv = *(const float4*)(b1 + col);
#pragma unroll
      for (int r = 0; r < 2; ++r) {
        __half2* d = (__half2*)(Xg + ((size_t)b * TT + t0 + ty * 2 + r) * NG + col);
        d[0] = __halves2half2(__float2half(acc[r][0] + bv.x),
                              __float2half(acc[r][1] + bv.y));
        d[1] = __halves2half2(__float2half(acc[r][2] + bv.z),
                              __float2half(acc[r][3] + bv.w));
      }
    }
    __syncthreads();
    if (n == 0) {
      __builtin_amdgcn_fence(__ATOMIC_RELEASE, "agent");
      atomicAdd(flagC + b * NCH + cc, 1u);
    }
  }
}

// ---- role B: layer-1 recurrence, 8 chains ----
__device__ __forceinline__ void roleB(int b, int n, char* smem,
    const __half* Xg, const float* __restrict__ Wh1,
    float* __restrict__ out, unsigned* flagC)
{
  const int j = n >> 2;
  const int p = n & 3;
  const bool tsel = (p == 2);

  h2_t wh[4][16];
#pragma unroll
  for (int g = 0; g < 4; ++g) {
    const float2* ph = (const float2*)(Wh1 + (size_t)(g * 128 + j) * HH + p * 32);
#pragma unroll
    for (int k = 0; k < 16; ++k) {
      float2 v = ph[k];
      wh[g][k][0] = (_Float16)v.x;
      wh[g][k][1] = (_Float16)v.y;
    }
  }

  _Float16(*hb)[HH] = (_Float16(*)[HH])smem;
  if (n < HH) {
    hb[0][n] = (_Float16)0.0f;
    hb[1][n] = (_Float16)0.0f;
  }
  float c = 0.0f, hv = 0.0f;
  __syncthreads();

  const __half* xs = Xg + (size_t)b * TT * NG + p * 128 + j;
  float* outp = out + (size_t)b * TT * HH;
  float* hT = out + (size_t)BB * TT * HH;
  float* cT = hT + 2 * BB * HH;

#pragma unroll 1
  for (int cc = 0; cc < NCH; ++cc) {
    if (n == 0) {
      while (aload(flagC + b * NCH + cc) < 2u) __builtin_amdgcn_s_sleep(1);
    }
    __syncthreads();
    __builtin_amdgcn_fence(__ATOMIC_ACQUIRE, "agent");

    __half xg_c = xs[(size_t)(cc * CH) * NG];
#pragma unroll 1
    for (int s = 0; s < CH; ++s) {
      const int i = cc * CH + s;
      __half xg_n = (s + 1 < CH) ? xs[(size_t)(i + 1) * NG] : __float2half(0.0f);

      const char* H = (const char*)hb[i & 1] + p * 64;
      float s0a = 0.f, s0b = 0.f, s1a = 0.f, s1b = 0.f;
      float s2a = 0.f, s2b = 0.f, s3a = 0.f, s3b = 0.f;
#pragma unroll
      for (int q = 0; q < 4; ++q) {
        LD4 u;
        u.f4 = *(const float4*)(H + q * 16);
        const int m = q * 4;
        s0a = fdot2f(wh[0][m + 0], u.h[0], s0a);
        s0b = fdot2f(wh[0][m + 2], u.h[2], s0b);
        s1a = fdot2f(wh[1][m + 0], u.h[0], s1a);
        s1b = fdot2f(wh[1][m + 2], u.h[2], s1b);
        s2a = fdot2f(wh[2][m + 0], u.h[0], s2a);
        s2b = fdot2f(wh[2][m + 2], u.h[2], s2b);
        s3a = fdot2f(wh[3][m + 0], u.h[0], s3a);
        s3b = fdot2f(wh[3][m + 2], u.h[2], s3b);
        s0a = fdot2f(wh[0][m + 1], u.h[1], s0a);
        s0b = fdot2f(wh[0][m + 3], u.h[3], s0b);
        s1a = fdot2f(wh[1][m + 1], u.h[1], s1a);
        s1b = fdot2f(wh[1][m + 3], u.h[3], s1b);
        s2a = fdot2f(wh[2][m + 1], u.h[1], s2a);
        s2b = fdot2f(wh[2][m + 3], u.h[3], s2b);
        s3a = fdot2f(wh[3][m + 1], u.h[1], s3a);
        s3b = fdot2f(wh[3][m + 3], u.h[3], s3b);
      }
      float a0 = s0a + s0b, a1 = s1a + s1b, a2 = s2a + s2b, a3 = s3a + s3b;

      float k01 = (p & 1) ? a1 : a0;
      float u01 = (p & 1) ? a0 : a1;
      float r01 = k01 + dpp_xor1(u01);
      float k23 = (p & 1) ? a3 : a2;
      float u23 = (p & 1) ? a2 : a3;
      float r23 = k23 + dpp_xor1(u23);
      float kA = (p & 2) ? r23 : r01;
      float uA = (p & 2) ? r01 : r23;
      float sL = kA + dpp_xor2(uA);
      float aL = act_gate(sL + __half2float(xg_c), tsel);
      float fg = dpp_xor1(aL);
      float gg = dpp_xor2(aL);
      float og = dpp_xor2(fg);
      if (p == 0) {
        c = fg * c + aL * gg;
        hv = og * fast_tanh(c);
        hb[(i & 1) ^ 1][j] = (_Float16)hv;
        outp[(size_t)i * HH + j] = hv;
      }
      bar_lds();
      xg_c = xg_n;
    }
  }

  if (p == 0) {
    hT[BB * HH + b * HH + j] = hv;
    cT[BB * HH + b * HH + j] = c;
  }
}

__global__
__attribute__((amdgpu_flat_work_group_size(512, 512)))
void lstm_mega(__half* Xg, __half* hstream, const float* __restrict__ x,
               const float* __restrict__ Wh0,
               const float* __restrict__ Wh1,
               const float* __restrict__ WT0,
               const float* __restrict__ b0,
               const float* __restrict__ WT1,
               const float* __restrict__ b1,
               float* __restrict__ out,
               unsigned* flag0, unsigned* flagC, unsigned* flagX)
{
  __shared__ __align__(16) char smem[64 * 68 * 4 + 64 * 64 * 4];  // 33792B
  const int bid = blockIdx.x;
  const int n = threadIdx.x;
  if (bid < BB) {
    roleA(bid, n, smem, Xg, Wh0, out, hstream, flag0, flagX);
  } else if (bid < BB + 2 * BB) {
    roleC(bid - BB, n, smem, Xg, hstream, x, WT0, b0, WT1, b1,
          flag0, flagC, flagX);
  } else {
    roleB(bid - 3 * BB, n, smem, Xg, Wh1, out, flagC);
  }
}

// ---------------------------------------------------------------------------
extern "C" void kernel_launch(void* const* d_in, const int* in_sizes, int n_in,
                              void* d_out, int out_size, void* d_ws, size_t ws_size,
                              hipStream_t stream) {
  const float* x   = (const float*)d_in[0];
  const float* Wx0 = (const float*)d_in[1];
  const float* Wh0 = (const float*)d_in[2];
  const float* b0  = (const float*)d_in[3];
  const float* Wx1 = (const float*)d_in[4];
  const float* Wh1 = (const float*)d_in[5];
  const float* b1  = (const float*)d_in[6];
  float* out = (float*)d_out;

  // ws: Xg f16 [B*T][512] | hstream f16 [B*T][128] | WT0 | WT1 | flags x3
  char* base = (char*)d_ws;
  __half* Xg = (__half*)base;
  size_t off = (size_t)BB * TT * NG * sizeof(__half);      // 128 MB
  __half* hstream = (__half*)(base + off);
  off += (size_t)BB * TT * HH * sizeof(__half);            // +32 MB
  float* WT0 = (float*)(base + off);
  off += (size_t)II * NG * sizeof(float);
  float* WT1 = (float*)(base + off);
  off += (size_t)II * NG * sizeof(float);
  unsigned* flag0 = (unsigned*)(base + off);
  unsigned* flagC = flag0 + BB * NCH;
  unsigned* flagX = flagC + BB * NCH;

  hipMemsetAsync(flag0, 0, 3 * (size_t)BB * NCH * sizeof(unsigned), stream);
  w_transpose2<<<512, 256, 0, stream>>>(Wx0, WT0, Wx1, WT1);
  // Prologue: Xg0 for chunks 0..1 (rows [b*TT, b*TT+256))
  xg_gemm_pro<<<dim3(BB * 4, NG / 64), 256, 0, stream>>>(x, WT0, b0, Xg);
  lstm_mega<<<4 * BB, 512, 0, stream>>>(Xg, hstream, x, Wh0, Wh1, WT0, b0,
                                        WT1, b1, out, flag0, flagC, flagX);
}

// Round 14
// 1414.886 us; speedup vs baseline: 3.0723x; 1.0127x over previous
//
#include <hip/hip_runtime.h>
#include <hip/hip_fp16.h>

// Problem constants
#define BB 64
#define TT 2048
#define II 128
#define HH 128
#define NG 512   // 4*H
#define CH 128   // pipeline chunk (steps)
#define NCH (TT / CH)
#define DYN_LDS 81984  // > 160KiB/2 -> hardware can place only ONE WG per CU

typedef _Float16 h2_t __attribute__((ext_vector_type(2)));

#if defined(__has_builtin)
#if __has_builtin(__builtin_amdgcn_fdot2)
#define HAVE_FDOT2 1
#endif
#endif

__device__ __forceinline__ float fdot2f(h2_t a, h2_t b, float c) {
#ifdef HAVE_FDOT2
  return __builtin_amdgcn_fdot2(a, b, c, false);
#else
  return c + (float)a[0] * (float)b[0] + (float)a[1] * (float)b[1];
#endif
}

__device__ __forceinline__ float fast_sigmoid(float x) {
  float t = __builtin_amdgcn_exp2f(-1.4426950408889634f * x);
  return __builtin_amdgcn_rcpf(1.0f + t);
}
__device__ __forceinline__ float act_gate(float x, bool tanh_sel) {
  float xx = tanh_sel ? 2.0f * x : x;
  float s = fast_sigmoid(xx);
  return tanh_sel ? 2.0f * s - 1.0f : s;
}
__device__ __forceinline__ float fast_tanh(float x) {
  return 2.0f * fast_sigmoid(2.0f * x) - 1.0f;
}

__device__ __forceinline__ float dpp_xor1(float x) {
  return __int_as_float(__builtin_amdgcn_update_dpp(0, __float_as_int(x), 0xB1, 0xF, 0xF, true));
}
__device__ __forceinline__ float dpp_xor2(float x) {
  return __int_as_float(__builtin_amdgcn_update_dpp(0, __float_as_int(x), 0x4E, 0xF, 0xF, true));
}

// LDS-only barrier: lgkmcnt drain + s_barrier (no vmcnt drain).
__device__ __forceinline__ void bar_lds() {
  __builtin_amdgcn_fence(__ATOMIC_RELEASE, "workgroup", "local");
  __builtin_amdgcn_s_barrier();
  __builtin_amdgcn_fence(__ATOMIC_ACQUIRE, "workgroup", "local");
}

union LD4 {
  float4 f4;
  h2_t h[4];
};
union LDB {
  uint4 u4;
  h2_t h[4];
};

__device__ __forceinline__ unsigned aload(unsigned* p) { return atomicAdd(p, 0u); }

// ---------------------------------------------------------------------------
// Transpose both Wx0 and Wx1: [512][128] -> [128][512]
// ---------------------------------------------------------------------------
__global__ void w_transpose2(const float* __restrict__ W0, float* __restrict__ T0,
                             const float* __restrict__ W1, float* __restrict__ T1) {
  int bid = blockIdx.x;
  const float* W = (bid < 256) ? W0 : W1;
  float* T = (bid < 256) ? T0 : T1;
  int idx = (bid & 255) * 256 + threadIdx.x;
  int n = idx >> 7;
  int k = idx & 127;
  T[k * NG + n] = W[idx];
}

// ---------------------------------------------------------------------------
// Prologue GEMM: Xg0 for chunks 0..1 only (rows [b*TT, b*TT+2*CH) per batch).
// grid.x = BB*4 (4 row-blocks of 64 = 256 rows/batch), grid.y = 8.
// ---------------------------------------------------------------------------
__global__ __launch_bounds__(256) void xg_gemm_pro(const float* __restrict__ X,
                                                   const float* __restrict__ WT,
                                                   const float* __restrict__ bias,
                                                   __half* __restrict__ Xg) {
  __shared__ float As[64][132];
  __shared__ float Bs[128][64];
  const int bx = blockIdx.x;
  const size_t m0 = (size_t)(bx >> 2) * TT + (bx & 3) * 64;
  const int n0 = blockIdx.y * 64;
  const int tid = threadIdx.x;

  {
    const float4* xv = (const float4*)(X + m0 * II);
#pragma unroll
    for (int r = 0; r < 8; ++r) {
      int f = tid + 256 * r;
      int m = f >> 5;
      int c4 = f & 31;
      float4 v = xv[m * 32 + c4];
      *(float4*)&As[m][c4 * 4] = v;
    }
  }
  {
#pragma unroll
    for (int r = 0; r < 8; ++r) {
      int f = tid + 256 * r;
      int k = f >> 4;
      int q = f & 15;
      float4 v = *(const float4*)(WT + (size_t)k * NG + n0 + q * 4);
      *(float4*)&Bs[k][q * 4] = v;
    }
  }
  __syncthreads();

  const int tx = tid & 15;
  const int ty = tid >> 4;
  float acc[4][4];
#pragma unroll
  for (int i = 0; i < 4; ++i)
#pragma unroll
    for (int j = 0; j < 4; ++j) acc[i][j] = 0.0f;

#pragma unroll 4
  for (int k = 0; k < 128; ++k) {
    float a0 = As[ty * 4 + 0][k];
    float a1 = As[ty * 4 + 1][k];
    float a2 = As[ty * 4 + 2][k];
    float a3 = As[ty * 4 + 3][k];
    float4 bv = *(const float4*)&Bs[k][tx * 4];
    acc[0][0] = fmaf(a0, bv.x, acc[0][0]);
    acc[0][1] = fmaf(a0, bv.y, acc[0][1]);
    acc[0][2] = fmaf(a0, bv.z, acc[0][2]);
    acc[0][3] = fmaf(a0, bv.w, acc[0][3]);
    acc[1][0] = fmaf(a1, bv.x, acc[1][0]);
    acc[1][1] = fmaf(a1, bv.y, acc[1][1]);
    acc[1][2] = fmaf(a1, bv.z, acc[1][2]);
    acc[1][3] = fmaf(a1, bv.w, acc[1][3]);
    acc[2][0] = fmaf(a2, bv.x, acc[2][0]);
    acc[2][1] = fmaf(a2, bv.y, acc[2][1]);
    acc[2][2] = fmaf(a2, bv.z, acc[2][2]);
    acc[2][3] = fmaf(a2, bv.w, acc[2][3]);
    acc[3][0] = fmaf(a3, bv.x, acc[3][0]);
    acc[3][1] = fmaf(a3, bv.y, acc[3][1]);
    acc[3][2] = fmaf(a3, bv.z, acc[3][2]);
    acc[3][3] = fmaf(a3, bv.w, acc[3][3]);
  }

  float4 bvec = *(const float4*)(bias + n0 + tx * 4);
#pragma unroll
  for (int i = 0; i < 4; ++i) {
    size_t m = m0 + ty * 4 + i;
    __half2* dst = (__half2*)(Xg + m * NG + n0 + tx * 4);
    dst[0] = __halves2half2(__float2half(acc[i][0] + bvec.x),
                            __float2half(acc[i][1] + bvec.y));
    dst[1] = __halves2half2(__float2half(acc[i][2] + bvec.z),
                            __float2half(acc[i][3] + bvec.w));
  }
}

// ===========================================================================
// Mega kernel: 256 WGs, ONE per CU (DYN_LDS > LDS/2 forbids packing).
//   [0,64):    role A — L0 recurrence (waits flagX for cc>=2), flag0/chunk
//   [64,192):  role C — per iter cc: Xg0(cc+2)=x@Wx0^T+b0 -> flagX, then
//              wait flag0(cc) -> Xg1(cc)=h0@Wx1^T+b1 (in place) -> flagC
//   [192,256): role B — L1 recurrence on Xg1 chunks (waits flagC>=2)
// ===========================================================================

// ---- role A: layer-0 recurrence, 8 accumulation chains ----
__device__ __forceinline__ void roleA(int b, int n, char* smem,
    const __half* Xg, const float* __restrict__ Wh0,
    float* __restrict__ out, __half* hstream,
    unsigned* flag0, unsigned* flagX)
{
  const int j = n >> 2;
  const int p = n & 3;
  const bool tsel = (p == 2);

  h2_t wh[4][16];
#pragma unroll
  for (int g = 0; g < 4; ++g) {
    const float2* ph = (const float2*)(Wh0 + (size_t)(g * 128 + j) * HH + p * 32);
#pragma unroll
    for (int k = 0; k < 16; ++k) {
      float2 v = ph[k];
      wh[g][k][0] = (_Float16)v.x;
      wh[g][k][1] = (_Float16)v.y;
    }
  }

  _Float16(*hb)[HH] = (_Float16(*)[HH])smem;
  if (n < HH) {
    hb[0][n] = (_Float16)0.0f;
    hb[1][n] = (_Float16)0.0f;
  }
  float c = 0.0f, hv = 0.0f;
  __syncthreads();

  const __half* xs = Xg + (size_t)b * TT * NG + p * 128 + j;
  float* hT = out + (size_t)BB * TT * HH;
  float* cT = hT + 2 * BB * HH;
  __half* hsp = hstream + (size_t)b * TT * HH + j;

#pragma unroll 1
  for (int cc = 0; cc < NCH; ++cc) {
    if (cc >= 2) {
      if (n == 0) {
        while (aload(flagX + b * NCH + cc) < 2u) __builtin_amdgcn_s_sleep(1);
      }
      __syncthreads();
      __builtin_amdgcn_fence(__ATOMIC_ACQUIRE, "agent");
    }
    __half xg_c = xs[(size_t)(cc * CH) * NG];

#pragma unroll 1
    for (int s = 0; s < CH; ++s) {
      const int i = cc * CH + s;
      __half xg_n = (s + 1 < CH) ? xs[(size_t)(i + 1) * NG] : __float2half(0.0f);

      const char* H = (const char*)hb[i & 1] + p * 64;
      float s0a = 0.f, s0b = 0.f, s1a = 0.f, s1b = 0.f;
      float s2a = 0.f, s2b = 0.f, s3a = 0.f, s3b = 0.f;
#pragma unroll
      for (int q = 0; q < 4; ++q) {
        LD4 u;
        u.f4 = *(const float4*)(H + q * 16);
        const int m = q * 4;
        s0a = fdot2f(wh[0][m + 0], u.h[0], s0a);
        s0b = fdot2f(wh[0][m + 2], u.h[2], s0b);
        s1a = fdot2f(wh[1][m + 0], u.h[0], s1a);
        s1b = fdot2f(wh[1][m + 2], u.h[2], s1b);
        s2a = fdot2f(wh[2][m + 0], u.h[0], s2a);
        s2b = fdot2f(wh[2][m + 2], u.h[2], s2b);
        s3a = fdot2f(wh[3][m + 0], u.h[0], s3a);
        s3b = fdot2f(wh[3][m + 2], u.h[2], s3b);
        s0a = fdot2f(wh[0][m + 1], u.h[1], s0a);
        s0b = fdot2f(wh[0][m + 3], u.h[3], s0b);
        s1a = fdot2f(wh[1][m + 1], u.h[1], s1a);
        s1b = fdot2f(wh[1][m + 3], u.h[3], s1b);
        s2a = fdot2f(wh[2][m + 1], u.h[1], s2a);
        s2b = fdot2f(wh[2][m + 3], u.h[3], s2b);
        s3a = fdot2f(wh[3][m + 1], u.h[1], s3a);
        s3b = fdot2f(wh[3][m + 3], u.h[3], s3b);
      }
      float a0 = s0a + s0b, a1 = s1a + s1b, a2 = s2a + s2b, a3 = s3a + s3b;

      float k01 = (p & 1) ? a1 : a0;
      float u01 = (p & 1) ? a0 : a1;
      float r01 = k01 + dpp_xor1(u01);
      float k23 = (p & 1) ? a3 : a2;
      float u23 = (p & 1) ? a2 : a3;
      float r23 = k23 + dpp_xor1(u23);
      float kA = (p & 2) ? r23 : r01;
      float uA = (p & 2) ? r01 : r23;
      float sL = kA + dpp_xor2(uA);
      float aL = act_gate(sL + __half2float(xg_c), tsel);
      float fg = dpp_xor1(aL);
      float gg = dpp_xor2(aL);
      float og = dpp_xor2(fg);
      if (p == 0) {
        c = fg * c + aL * gg;
        hv = og * fast_tanh(c);
        _Float16 hf = (_Float16)hv;
        hb[(i & 1) ^ 1][j] = hf;
        *(_Float16*)(hsp + (size_t)i * HH) = hf;
      }
      bar_lds();
      xg_c = xg_n;
    }
    __syncthreads();   // drains hstream stores (vmcnt)
    if (n == 0) {
      __builtin_amdgcn_fence(__ATOMIC_RELEASE, "agent");
      atomicExch(flag0 + b * NCH + cc, 1u);
    }
  }

  if (p == 0) {
    hT[b * HH + j] = hv;
    cT[b * HH + j] = c;
  }
}

// ---- role C: Xg0(cc+2) production then Xg1(cc) bridge GEMM ----
__device__ __forceinline__ void roleC(int cidx, int n, char* smem,
    __half* Xg, const __half* hstream, const float* __restrict__ x,
    const float* __restrict__ WT0, const float* __restrict__ b0,
    const float* __restrict__ WT1, const float* __restrict__ b1,
    unsigned* flag0, unsigned* flagC, unsigned* flagX)
{
  const int b = cidx >> 1;
  const int half = cidx & 1;
  h2_t(*As2)[68] = (h2_t(*)[68])smem;                    // [64][68] h2
  h2_t(*Bs2)[64] = (h2_t(*)[64])(smem + 64 * 68 * 4);    // [64][64] h2

  const int ty = n >> 4;
  const int tx = n & 15;
  const int mf = n >> 3;   // fill row
  const int sf = n & 7;    // fill segment

#pragma unroll 1
  for (int cc = 0; cc < NCH; ++cc) {
    // ======== part X0: Xg0 for chunk cc+2 (input-only, no waits) ========
    if (cc + 2 < NCH) {
      const int t0x = (cc + 2) * CH + half * 64;
      {
        const float4* sx = (const float4*)(x + ((size_t)b * TT + t0x + mf) * II + sf * 16);
        float4 p0 = sx[0], p1 = sx[1], p2 = sx[2], p3 = sx[3];
        h2_t r[8];
        r[0][0] = (_Float16)p0.x; r[0][1] = (_Float16)p0.y;
        r[1][0] = (_Float16)p0.z; r[1][1] = (_Float16)p0.w;
        r[2][0] = (_Float16)p1.x; r[2][1] = (_Float16)p1.y;
        r[3][0] = (_Float16)p1.z; r[3][1] = (_Float16)p1.w;
        r[4][0] = (_Float16)p2.x; r[4][1] = (_Float16)p2.y;
        r[5][0] = (_Float16)p2.z; r[5][1] = (_Float16)p2.w;
        r[6][0] = (_Float16)p3.x; r[6][1] = (_Float16)p3.y;
        r[7][0] = (_Float16)p3.z; r[7][1] = (_Float16)p3.w;
        *(uint4*)&As2[mf][sf * 8] = *(uint4*)&r[0];
        *(uint4*)&As2[mf][sf * 8 + 4] = *(uint4*)&r[4];
      }
#pragma unroll 1
      for (int nt = 0; nt < 8; ++nt) {
        __syncthreads();
        {
          const int kp = n >> 3, cg = n & 7;
          const float4* w0 = (const float4*)(WT0 + (size_t)(2 * kp) * NG + nt * 64 + cg * 8);
          const float4* w1 = (const float4*)(WT0 + (size_t)(2 * kp + 1) * NG + nt * 64 + cg * 8);
          float4 x0 = w0[0], x1 = w0[1];
          float4 y0 = w1[0], y1 = w1[1];
          h2_t r[8];
          r[0][0] = (_Float16)x0.x; r[0][1] = (_Float16)y0.x;
          r[1][0] = (_Float16)x0.y; r[1][1] = (_Float16)y0.y;
          r[2][0] = (_Float16)x0.z; r[2][1] = (_Float16)y0.z;
          r[3][0] = (_Float16)x0.w; r[3][1] = (_Float16)y0.w;
          r[4][0] = (_Float16)x1.x; r[4][1] = (_Float16)y1.x;
          r[5][0] = (_Float16)x1.y; r[5][1] = (_Float16)y1.y;
          r[6][0] = (_Float16)x1.z; r[6][1] = (_Float16)y1.z;
          r[7][0] = (_Float16)x1.w; r[7][1] = (_Float16)y1.w;
          *(uint4*)&Bs2[kp][cg * 8] = *(uint4*)&r[0];
          *(uint4*)&Bs2[kp][cg * 8 + 4] = *(uint4*)&r[4];
        }
        __syncthreads();

        float acc[2][4];
#pragma unroll
        for (int r = 0; r < 2; ++r)
#pragma unroll
          for (int q = 0; q < 4; ++q) acc[r][q] = 0.0f;
#pragma unroll 4
        for (int k4 = 0; k4 < 16; ++k4) {
          LDB ua0, ua1;
          ua0.u4 = *(const uint4*)&As2[ty * 2][k4 * 4];
          ua1.u4 = *(const uint4*)&As2[ty * 2 + 1][k4 * 4];
#pragma unroll
          for (int t = 0; t < 4; ++t) {
            LDB ub;
            ub.u4 = *(const uint4*)&Bs2[k4 * 4 + t][tx * 4];
            acc[0][0] = fdot2f(ua0.h[t], ub.h[0], acc[0][0]);
            acc[0][1] = fdot2f(ua0.h[t], ub.h[1], acc[0][1]);
            acc[0][2] = fdot2f(ua0.h[t], ub.h[2], acc[0][2]);
            acc[0][3] = fdot2f(ua0.h[t], ub.h[3], acc[0][3]);
            acc[1][0] = fdot2f(ua1.h[t], ub.h[0], acc[1][0]);
            acc[1][1] = fdot2f(ua1.h[t], ub.h[1], acc[1][1]);
            acc[1][2] = fdot2f(ua1.h[t], ub.h[2], acc[1][2]);
            acc[1][3] = fdot2f(ua1.h[t], ub.h[3], acc[1][3]);
          }
        }
        const int col = nt * 64 + tx * 4;
        float4 bv = *(const float4*)(b0 + col);
#pragma unroll
        for (int r = 0; r < 2; ++r) {
          __half2* d = (__half2*)(Xg + ((size_t)b * TT + t0x + ty * 2 + r) * NG + col);
          d[0] = __halves2half2(__float2half(acc[r][0] + bv.x),
                                __float2half(acc[r][1] + bv.y));
          d[1] = __halves2half2(__float2half(acc[r][2] + bv.z),
                                __float2half(acc[r][3] + bv.w));
        }
      }
      __syncthreads();   // drain Xg0 stores + protect As2
      if (n == 0) {
        __builtin_amdgcn_fence(__ATOMIC_RELEASE, "agent");
        atomicAdd(flagX + b * NCH + cc + 2, 1u);
      }
    }

    // ======== part X1: Xg1 for chunk cc (waits on h0) ========
    if (n == 0) {
      while (aload(flag0 + b * NCH + cc) < 1u) __builtin_amdgcn_s_sleep(8);
    }
    __syncthreads();
    __builtin_amdgcn_fence(__ATOMIC_ACQUIRE, "agent");

    const int t0 = cc * CH + half * 64;
    {
      const uint4* src = (const uint4*)(hstream + ((size_t)b * TT + t0 + mf) * HH + sf * 16);
      uint4 v0 = src[0], v1 = src[1];
      *(uint4*)&As2[mf][sf * 8] = v0;
      *(uint4*)&As2[mf][sf * 8 + 4] = v1;
    }
#pragma unroll 1
    for (int nt = 0; nt < 8; ++nt) {
      __syncthreads();
      {
        const int kp = n >> 3, cg = n & 7;
        const float4* w0 = (const float4*)(WT1 + (size_t)(2 * kp) * NG + nt * 64 + cg * 8);
        const float4* w1 = (const float4*)(WT1 + (size_t)(2 * kp + 1) * NG + nt * 64 + cg * 8);
        float4 x0 = w0[0], x1 = w0[1];
        float4 y0 = w1[0], y1 = w1[1];
        h2_t r[8];
        r[0][0] = (_Float16)x0.x; r[0][1] = (_Float16)y0.x;
        r[1][0] = (_Float16)x0.y; r[1][1] = (_Float16)y0.y;
        r[2][0] = (_Float16)x0.z; r[2][1] = (_Float16)y0.z;
        r[3][0] = (_Float16)x0.w; r[3][1] = (_Float16)y0.w;
        r[4][0] = (_Float16)x1.x; r[4][1] = (_Float16)y1.x;
        r[5][0] = (_Float16)x1.y; r[5][1] = (_Float16)y1.y;
        r[6][0] = (_Float16)x1.z; r[6][1] = (_Float16)y1.z;
        r[7][0] = (_Float16)x1.w; r[7][1] = (_Float16)y1.w;
        *(uint4*)&Bs2[kp][cg * 8] = *(uint4*)&r[0];
        *(uint4*)&Bs2[kp][cg * 8 + 4] = *(uint4*)&r[4];
      }
      __syncthreads();

      float acc[2][4];
#pragma unroll
      for (int r = 0; r < 2; ++r)
#pragma unroll
        for (int q = 0; q < 4; ++q) acc[r][q] = 0.0f;
#pragma unroll 4
      for (int k4 = 0; k4 < 16; ++k4) {
        LDB ua0, ua1;
        ua0.u4 = *(const uint4*)&As2[ty * 2][k4 * 4];
        ua1.u4 = *(const uint4*)&As2[ty * 2 + 1][k4 * 4];
#pragma unroll
        for (int t = 0; t < 4; ++t) {
          LDB ub;
          ub.u4 = *(const uint4*)&Bs2[k4 * 4 + t][tx * 4];
          acc[0][0] = fdot2f(ua0.h[t], ub.h[0], acc[0][0]);
          acc[0][1] = fdot2f(ua0.h[t], ub.h[1], acc[0][1]);
          acc[0][2] = fdot2f(ua0.h[t], ub.h[2], acc[0][2]);
          acc[0][3] = fdot2f(ua0.h[t], ub.h[3], acc[0][3]);
          acc[1][0] = fdot2f(ua1.h[t], ub.h[0], acc[1][0]);
          acc[1][1] = fdot2f(ua1.h[t], ub.h[1], acc[1][1]);
          acc[1][2] = fdot2f(ua1.h[t], ub.h[2], acc[1][2]);
          acc[1][3] = fdot2f(ua1.h[t], ub.h[3], acc[1][3]);
        }
      }
      const int col = nt * 64 + tx * 4;
      float4 bv = *(const float4*)(b1 + col);
#pragma unroll
      for (int r = 0; r < 2; ++r) {
        __half2* d = (__half2*)(Xg + ((size_t)b * TT + t0 + ty * 2 + r) * NG + col);
        d[0] = __halves2half2(__float2half(acc[r][0] + bv.x),
                              __float2half(acc[r][1] + bv.y));
        d[1] = __halves2half2(__float2half(acc[r][2] + bv.z),
                              __float2half(acc[r][3] + bv.w));
      }
    }
    __syncthreads();
    if (n == 0) {
      __builtin_amdgcn_fence(__ATOMIC_RELEASE, "agent");
      atomicAdd(flagC + b * NCH + cc, 1u);
    }
  }
}

// ---- role B: layer-1 recurrence, 8 chains ----
__device__ __forceinline__ void roleB(int b, int n, char* smem,
    const __half* Xg, const float* __restrict__ Wh1,
    float* __restrict__ out, unsigned* flagC)
{
  const int j = n >> 2;
  const int p = n & 3;
  const bool tsel = (p == 2);

  h2_t wh[4][16];
#pragma unroll
  for (int g = 0; g < 4; ++g) {
    const float2* ph = (const float2*)(Wh1 + (size_t)(g * 128 + j) * HH + p * 32);
#pragma unroll
    for (int k = 0; k < 16; ++k) {
      float2 v = ph[k];
      wh[g][k][0] = (_Float16)v.x;
      wh[g][k][1] = (_Float16)v.y;
    }
  }

  _Float16(*hb)[HH] = (_Float16(*)[HH])smem;
  if (n < HH) {
    hb[0][n] = (_Float16)0.0f;
    hb[1][n] = (_Float16)0.0f;
  }
  float c = 0.0f, hv = 0.0f;
  __syncthreads();

  const __half* xs = Xg + (size_t)b * TT * NG + p * 128 + j;
  float* outp = out + (size_t)b * TT * HH;
  float* hT = out + (size_t)BB * TT * HH;
  float* cT = hT + 2 * BB * HH;

#pragma unroll 1
  for (int cc = 0; cc < NCH; ++cc) {
    if (n == 0) {
      while (aload(flagC + b * NCH + cc) < 2u) __builtin_amdgcn_s_sleep(8);
    }
    __syncthreads();
    __builtin_amdgcn_fence(__ATOMIC_ACQUIRE, "agent");

    __half xg_c = xs[(size_t)(cc * CH) * NG];
#pragma unroll 1
    for (int s = 0; s < CH; ++s) {
      const int i = cc * CH + s;
      __half xg_n = (s + 1 < CH) ? xs[(size_t)(i + 1) * NG] : __float2half(0.0f);

      const char* H = (const char*)hb[i & 1] + p * 64;
      float s0a = 0.f, s0b = 0.f, s1a = 0.f, s1b = 0.f;
      float s2a = 0.f, s2b = 0.f, s3a = 0.f, s3b = 0.f;
#pragma unroll
      for (int q = 0; q < 4; ++q) {
        LD4 u;
        u.f4 = *(const float4*)(H + q * 16);
        const int m = q * 4;
        s0a = fdot2f(wh[0][m + 0], u.h[0], s0a);
        s0b = fdot2f(wh[0][m + 2], u.h[2], s0b);
        s1a = fdot2f(wh[1][m + 0], u.h[0], s1a);
        s1b = fdot2f(wh[1][m + 2], u.h[2], s1b);
        s2a = fdot2f(wh[2][m + 0], u.h[0], s2a);
        s2b = fdot2f(wh[2][m + 2], u.h[2], s2b);
        s3a = fdot2f(wh[3][m + 0], u.h[0], s3a);
        s3b = fdot2f(wh[3][m + 2], u.h[2], s3b);
        s0a = fdot2f(wh[0][m + 1], u.h[1], s0a);
        s0b = fdot2f(wh[0][m + 3], u.h[3], s0b);
        s1a = fdot2f(wh[1][m + 1], u.h[1], s1a);
        s1b = fdot2f(wh[1][m + 3], u.h[3], s1b);
        s2a = fdot2f(wh[2][m + 1], u.h[1], s2a);
        s2b = fdot2f(wh[2][m + 3], u.h[3], s2b);
        s3a = fdot2f(wh[3][m + 1], u.h[1], s3a);
        s3b = fdot2f(wh[3][m + 3], u.h[3], s3b);
      }
      float a0 = s0a + s0b, a1 = s1a + s1b, a2 = s2a + s2b, a3 = s3a + s3b;

      float k01 = (p & 1) ? a1 : a0;
      float u01 = (p & 1) ? a0 : a1;
      float r01 = k01 + dpp_xor1(u01);
      float k23 = (p & 1) ? a3 : a2;
      float u23 = (p & 1) ? a2 : a3;
      float r23 = k23 + dpp_xor1(u23);
      float kA = (p & 2) ? r23 : r01;
      float uA = (p & 2) ? r01 : r23;
      float sL = kA + dpp_xor2(uA);
      float aL = act_gate(sL + __half2float(xg_c), tsel);
      float fg = dpp_xor1(aL);
      float gg = dpp_xor2(aL);
      float og = dpp_xor2(fg);
      if (p == 0) {
        c = fg * c + aL * gg;
        hv = og * fast_tanh(c);
        hb[(i & 1) ^ 1][j] = (_Float16)hv;
        outp[(size_t)i * HH + j] = hv;
      }
      bar_lds();
      xg_c = xg_n;
    }
  }

  if (p == 0) {
    hT[BB * HH + b * HH + j] = hv;
    cT[BB * HH + b * HH + j] = c;
  }
}

__global__
__attribute__((amdgpu_flat_work_group_size(512, 512)))
void lstm_mega(__half* Xg, __half* hstream, const float* __restrict__ x,
               const float* __restrict__ Wh0,
               const float* __restrict__ Wh1,
               const float* __restrict__ WT0,
               const float* __restrict__ b0,
               const float* __restrict__ WT1,
               const float* __restrict__ b1,
               float* __restrict__ out,
               unsigned* flag0, unsigned* flagC, unsigned* flagX)
{
  extern __shared__ __align__(16) char smem[];   // DYN_LDS bytes: 1 WG/CU
  const int bid = blockIdx.x;
  const int n = threadIdx.x;
  if (bid < BB) {
    roleA(bid, n, smem, Xg, Wh0, out, hstream, flag0, flagX);
  } else if (bid < BB + 2 * BB) {
    roleC(bid - BB, n, smem, Xg, hstream, x, WT0, b0, WT1, b1,
          flag0, flagC, flagX);
  } else {
    roleB(bid - 3 * BB, n, smem, Xg, Wh1, out, flagC);
  }
}

// ---------------------------------------------------------------------------
extern "C" void kernel_launch(void* const* d_in, const int* in_sizes, int n_in,
                              void* d_out, int out_size, void* d_ws, size_t ws_size,
                              hipStream_t stream) {
  const float* x   = (const float*)d_in[0];
  const float* Wx0 = (const float*)d_in[1];
  const float* Wh0 = (const float*)d_in[2];
  const float* b0  = (const float*)d_in[3];
  const float* Wx1 = (const float*)d_in[4];
  const float* Wh1 = (const float*)d_in[5];
  const float* b1  = (const float*)d_in[6];
  float* out = (float*)d_out;

  // ws: Xg f16 [B*T][512] | hstream f16 [B*T][128] | WT0 | WT1 | flags x3
  char* base = (char*)d_ws;
  __half* Xg = (__half*)base;
  size_t off = (size_t)BB * TT * NG * sizeof(__half);      // 128 MB
  __half* hstream = (__half*)(base + off);
  off += (size_t)BB * TT * HH * sizeof(__half);            // +32 MB
  float* WT0 = (float*)(base + off);
  off += (size_t)II * NG * sizeof(float);
  float* WT1 = (float*)(base + off);
  off += (size_t)II * NG * sizeof(float);
  unsigned* flag0 = (unsigned*)(base + off);
  unsigned* flagC = flag0 + BB * NCH;
  unsigned* flagX = flagC + BB * NCH;

  static int attr_set = 0;
  hipFuncSetAttribute((const void*)lstm_mega,
                      hipFuncAttributeMaxDynamicSharedMemorySize, DYN_LDS);
  (void)attr_set;

  hipMemsetAsync(flag0, 0, 3 * (size_t)BB * NCH * sizeof(unsigned), stream);
  w_transpose2<<<512, 256, 0, stream>>>(Wx0, WT0, Wx1, WT1);
  // Prologue: Xg0 for chunks 0..1 (rows [b*TT, b*TT+256))
  xg_gemm_pro<<<dim3(BB * 4, NG / 64), 256, 0, stream>>>(x, WT0, b0, Xg);
  lstm_mega<<<4 * BB, 512, DYN_LDS, stream>>>(Xg, hstream, x, Wh0, Wh1, WT0,
                                              b0, WT1, b1, out, flag0, flagC,
                                              flagX);
}